// Round 6
// baseline (19.485 us; speedup 1.0000x reference)
//
#include <hip/hip_runtime.h>

#define NN 64
#define KK 64
#define BETA_C 0.9f

// Single fused kernel. Block = (b, i, m-half). 1024 threads = 16 waves.
// Phase A: stage W + mask; waves 0..7 compute g1[b,i,:,:] -> LDS (8 rows/wave);
//          meanwhile ALL waves pre-issue their first walk load batch (L2 latency
//          hides under the GEMM FMAs).
// Phase B: wave w handles m0 = mh*32+2w (lanes 0..31) and m1 = m0+1 (lanes 32..63),
//          each lane owning a k-pair (float2). Separate sparse j-lists per m,
//          extracted in scalar SALU, loads double-buffered (batch n+1 in flight
//          while batch n is consumed).
__global__ __launch_bounds__(1024, 4) void walk_fused2(const float* __restrict__ graph,
                                                       const float* __restrict__ W,
                                                       const int* __restrict__ mask,
                                                       float* __restrict__ out) {
    __shared__ float Ws[KK][KK];    // 16 KB, Ws[k][l]
    __shared__ float g1s[NN][KK];   // 16 KB
    __shared__ int   ms[NN][33];    // 8.25 KB, pad 33 -> <=2-way (free)

    int bid = blockIdx.x;
    int b, i, mh;
    if (gridDim.x == 256) {
        // XCD-clustered decode: same bid%8 -> same XCD; that XCD's blocks share
        // the gcol working set graph[b,:,mh-half,:] (2 MB, fits one 4 MB L2).
        int xcdsel = bid & 7;
        b  = xcdsel >> 2;
        mh = (xcdsel >> 1) & 1;
        i  = ((xcdsel & 1) << 5) | (bid >> 3);
    } else {
        mh = bid & 1;
        i  = (bid >> 1) & 63;
        b  = bid >> 7;
    }

    int t    = threadIdx.x;
    int lane = t & 63;                                   // k (doubles as j for ballot)
    int w    = __builtin_amdgcn_readfirstlane(t >> 6);   // wave id 0..15, SGPR

    size_t biBase = (size_t)(b * NN + i);

    // ---- stage W (one float4 per thread) ----
    ((float4*)&Ws[0][0])[t] = ((const float4*)W)[t];

    // ---- stage mask[b,i,:,mh*32 .. mh*32+31] (2 ints per thread) ----
    {
        const int* mbase = mask + (biBase * NN) * NN + mh * 32;
        int j = t >> 5, c = t & 31;
        ms[j][c]      = mbase[(size_t)j * NN + c];
        ms[j + 32][c] = mbase[(size_t)(j + 32) * NN + c];
    }
    __syncthreads();

    // ---- walk setup: validity bitmasks (lane plays j) ----
    int m0 = mh * 32 + 2 * w;
    int m1 = m0 + 1;
    bool v0 = (ms[lane][2 * w + 0] != 0) & (lane != m0) & (lane != i);
    bool v1 = (ms[lane][2 * w + 1] != 0) & (lane != m1) & (lane != i);
    unsigned long long vm0 = __ballot(v0);               // SGPR pair
    unsigned long long vm1 = __ballot(v1);
    if (i == m0) vm0 = 0ULL;
    if (i == m1) vm1 = 0ULL;

    int half = lane >> 5;                  // 0 -> m0, 1 -> m1
    int kp   = lane & 31;                  // k-pair: k = {2kp, 2kp+1}
    int mlane = half ? m1 : m0;
    int vbase = mlane * 32 + kp;           // float2 offset of (m, k-pair) in a j-slab

    const float2* gb2 = (const float2*)(graph + (size_t)b * NN * NN * KK);
    const float2* g1p = (const float2*)&g1s[0][0];

    // batch extract (scalar) + issue global loads (8 float2 per lane)
    auto extract_issue = [&](int* jvv, bool* kll, float2* gvv) {
#pragma unroll
        for (int n = 0; n < 8; ++n) {
            bool l0n = (vm0 != 0ULL);
            int  j0  = (int)__builtin_ctzll(l0n ? vm0 : 1ULL);
            vm0 &= vm0 - 1ULL;
            bool l1n = (vm1 != 0ULL);
            int  j1  = (int)__builtin_ctzll(l1n ? vm1 : 1ULL);
            vm1 &= vm1 - 1ULL;
            int j   = half ? j1 : j0;      // per-lane-half select
            kll[n]  = half ? l1n : l0n;
            jvv[n]  = j;
            gvv[n]  = gb2[(size_t)j * (NN * KK / 2) + vbase];
        }
    };

    // ---- peel batch 0: issue its global loads BEFORE the GEMM ----
    float2 gvA[8]; int jvA[8]; bool klA[8];
    bool haveA = ((vm0 | vm1) != 0ULL);
    if (haveA) extract_issue(jvA, klA, gvA);

    // ---- Phase A: GEMM g1s = graph[b,i,:,:] @ W, waves 0..7, 8 rows each ----
    if (w < 8) {
        int r0 = w * 8;
        const float4* a = (const float4*)(graph + (biBase * NN + r0) * KK); // 16 f4/row
        float acc[8] = {0.f, 0.f, 0.f, 0.f, 0.f, 0.f, 0.f, 0.f};
#pragma unroll
        for (int k4 = 0; k4 < 16; ++k4) {
            float4 x[8];
#pragma unroll
            for (int r = 0; r < 8; ++r) x[r] = a[k4 + 16 * r];   // broadcast loads
            float w0 = Ws[4 * k4 + 0][lane];
            float w1 = Ws[4 * k4 + 1][lane];
            float w2 = Ws[4 * k4 + 2][lane];
            float w3 = Ws[4 * k4 + 3][lane];
#pragma unroll
            for (int r = 0; r < 8; ++r) {
                acc[r] = fmaf(x[r].x, w0, acc[r]);
                acc[r] = fmaf(x[r].y, w1, acc[r]);
                acc[r] = fmaf(x[r].z, w2, acc[r]);
                acc[r] = fmaf(x[r].w, w3, acc[r]);
            }
        }
#pragma unroll
        for (int r = 0; r < 8; ++r) g1s[r0 + r][lane] = acc[r];
    }
    __syncthreads();

    // ---- Phase B: double-buffered walk ----
    float accx = 0.f, absx = 0.f, accy = 0.f, absy = 0.f;
    while (haveA) {
        bool haveB = ((vm0 | vm1) != 0ULL);
        float2 gvB[8]; int jvB[8]; bool klB[8];
        if (haveB) extract_issue(jvB, klB, gvB);   // next batch in flight
#pragma unroll
        for (int n = 0; n < 8; ++n) {
            float2 gw = g1p[jvA[n] * (KK / 2) + kp];
            float px = klA[n] ? gvA[n].x * gw.x : 0.f;
            float py = klA[n] ? gvA[n].y * gw.y : 0.f;
            accx += px; absx += fabsf(px);
            accy += py; absy += fabsf(py);
        }
        haveA = haveB;
#pragma unroll
        for (int n = 0; n < 8; ++n) { gvA[n] = gvB[n]; jvA[n] = jvB[n]; klA[n] = klB[n]; }
    }

    // ---- epilogue: lerp with beta, dwordx2 ----
    {
        size_t o2 = (biBase * NN + mlane) * (KK / 2) + kp;
        float2 old = ((const float2*)graph)[o2];
        float nwx = (accx + absx) * 0.5f;             // == sum(relu(p)) exactly
        float nwy = (accy + absy) * 0.5f;
        float bx = (absx != 0.f) ? BETA_C : 1.0f;     // anynz <=> sum|p| != 0
        float by = (absy != 0.f) ? BETA_C : 1.0f;
        float2 res;
        res.x = nwx + bx * (old.x - nwx);
        res.y = nwy + by * (old.y - nwy);
        ((float2*)out)[o2] = res;
    }
}

extern "C" void kernel_launch(void* const* d_in, const int* in_sizes, int n_in,
                              void* d_out, int out_size, void* d_ws, size_t ws_size,
                              hipStream_t stream) {
    const float* graph = (const float*)d_in[0];
    const float* W     = (const float*)d_in[1];
    const int*   mask  = (const int*)d_in[2];
    float*       out   = (float*)d_out;

    int B = in_sizes[0] / (NN * NN * KK);     // 2
    walk_fused2<<<B * NN * 2, 1024, 0, stream>>>(graph, W, mask, out);
}